// Round 8
// baseline (277.371 us; speedup 1.0000x reference)
//
#include <hip/hip_runtime.h>
#include <hip/hip_bf16.h>
#include <stdint.h>

#define M_DIM 8192
#define N_DIM 4096
#define K_DIM 4096
#define BM 256
#define BN 256
#define BK 64
#define NT (K_DIM / BK)    // 64 K-tiles
#define THREADS 512
#define NBLOCKS_VQ (N_DIM * K_DIM / 16)

#define ABUF_B 32768       // one A (or B) K-tile: 256 x 64 x 2B
#define BREG   65536       // B region base
#define SMEM_BYTES 131072

typedef short bf16x8 __attribute__((ext_vector_type(8)));
typedef float f32x4 __attribute__((ext_vector_type(4)));
typedef unsigned short ushort_t;
typedef ushort_t ushort8 __attribute__((ext_vector_type(8)));

#define GLOBAL_AS __attribute__((address_space(1)))
#define LDS_AS __attribute__((address_space(3)))

__device__ __forceinline__ ushort_t f2bf(float f) {
  union { float f; uint32_t u; } v; v.f = f;
  uint32_t u = v.u;
  return (ushort_t)((u + 0x7FFFu + ((u >> 16) & 1u)) >> 16);
}

// ---------------- dequant: W[j][k] = coarse[cl[b]] + res[rl[b]], block b of 16
__global__ __launch_bounds__(256) void dequant_w(
    const float* __restrict__ cc, const int* __restrict__ cl,
    const float* __restrict__ rc, const int* __restrict__ rl,
    ushort_t* __restrict__ wout) {
  int b = blockIdx.x * 256 + threadIdx.x;
  int ci = cl[b];
  int ri = rl[b];
  const float4* c4 = (const float4*)(cc + (size_t)ci * 16);
  const float4* r4 = (const float4*)(rc + (size_t)ri * 16);
  float s[16];
#pragma unroll
  for (int p = 0; p < 4; ++p) {
    float4 a = c4[p];
    float4 r = r4[p];
    s[p * 4 + 0] = a.x + r.x;
    s[p * 4 + 1] = a.y + r.y;
    s[p * 4 + 2] = a.z + r.z;
    s[p * 4 + 3] = a.w + r.w;
  }
  ushort8 o0, o1;
#pragma unroll
  for (int j = 0; j < 8; ++j) o0[j] = f2bf(s[j]);
#pragma unroll
  for (int j = 0; j < 8; ++j) o1[j] = f2bf(s[8 + j]);
  ushort8* dst = (ushort8*)(wout + (size_t)b * 16);
  dst[0] = o0;
  dst[1] = o1;
}

// ---------------- x fp32 -> bf16
__global__ __launch_bounds__(256) void cvt_x_bf16(const float* __restrict__ x,
                                                  ushort_t* __restrict__ xb) {
  size_t i = (size_t)blockIdx.x * 256 + threadIdx.x;
  const float4* p = (const float4*)x + i * 2;
  float4 a = p[0];
  float4 b = p[1];
  ushort8 o;
  o[0] = f2bf(a.x); o[1] = f2bf(a.y); o[2] = f2bf(a.z); o[3] = f2bf(a.w);
  o[4] = f2bf(b.x); o[5] = f2bf(b.y); o[6] = f2bf(b.z); o[7] = f2bf(b.w);
  ((ushort8*)xb)[i] = o;
}

// ---------------- staging state
struct SP {
  const ushort_t* gA;  // per-thread A source (tile 0, inverse-swizzled col)
  const ushort_t* gB;  // per-thread B source (tile 0, permuted row, swz col)
  char* sm;
  int wuni;            // wave*1024 (wave-uniform LDS offset; HW appends lane*16)
};

__device__ __forceinline__ void stA(const SP& s, int r, int tile, int dbuf) {
  __builtin_amdgcn_global_load_lds(
      (const GLOBAL_AS void*)(s.gA + (size_t)tile * BK + (size_t)r * 64 * K_DIM),
      (LDS_AS void*)(s.sm + dbuf * ABUF_B + r * 8192 + s.wuni), 16, 0, 0);
}
__device__ __forceinline__ void stB(const SP& s, int r, int tile, int dbuf) {
  // LDS B row order is n-half-major: round r covers these global row offsets
  constexpr int roff[4] = {0, 128, 32, 160};
  __builtin_amdgcn_global_load_lds(
      (const GLOBAL_AS void*)(s.gB + (size_t)tile * BK + (size_t)roff[r] * K_DIM),
      (LDS_AS void*)(s.sm + BREG + dbuf * ABUF_B + r * 8192 + s.wuni), 16, 0, 0);
}

#define BAR()  __builtin_amdgcn_s_barrier()
#define SCB()  __builtin_amdgcn_sched_barrier(0)
#define LGKM0() do { asm volatile("s_waitcnt lgkmcnt(0)" ::: "memory"); SCB(); } while (0)
#define VMC(n) asm volatile("s_waitcnt vmcnt(" #n ")" ::: "memory")

#define MFMA_Q(ACCM, AARR, BARR, ACCN)                                           \
  __builtin_amdgcn_s_setprio(1);                                                 \
  _Pragma("unroll")                                                              \
  for (int m = 0; m < 4; ++m)                                                    \
    _Pragma("unroll")                                                            \
    for (int ni = 0; ni < 2; ++ni) {                                             \
      acc[ACCM + m][ACCN + ni] = __builtin_amdgcn_mfma_f32_16x16x32_bf16(        \
          AARR[m * 2 + 0], BARR[ni * 2 + 0], acc[ACCM + m][ACCN + ni], 0, 0, 0); \
      acc[ACCM + m][ACCN + ni] = __builtin_amdgcn_mfma_f32_16x16x32_bf16(        \
          AARR[m * 2 + 1], BARR[ni * 2 + 1], acc[ACCM + m][ACCN + ni], 0, 0, 0); \
    }                                                                            \
  __builtin_amdgcn_s_setprio(0);

// m201-shape phases: {ds_reads Q(i) | stage G(i) | vmcnt | BAR | lgkm0 |
// MFMA Q(i) | BAR}. Quadrant reads: p1 A-m0(G1)+B-n0(G2), p2 B-n1(G3),
// p3 A-m1(G4), p4 none. Stage order G1..G4 of tile t+1 at p1..p4.
// Steady-state certification: vmcnt(4) at p1-end (G3 of t), p2-end (G4 of t),
// p4-end (G1,G2 of t+1); p3 needs none. Every load keeps 2-3 phases in flight.
template<bool ISSUE, bool LAST>
__device__ __forceinline__ void ktile(const SP& sp, int buf, int t,
    int aBase, int bBase, int sw0, int sw1, f32x4 (&acc)[8][4]) {
  const ushort_t* bufA = (const ushort_t*)(sp.sm + buf * ABUF_B);
  const ushort_t* bufB = (const ushort_t*)(sp.sm + BREG + buf * ABUF_B);
  bf16x8 a[8], b0[4], b1[4];

  // ---- phase 1: reads A-m0(8) + B-n0(4); MFMA (m0,n0)
#pragma unroll
  for (int m = 0; m < 4; ++m) {
    a[m * 2 + 0] = *(const bf16x8*)(bufA + aBase + m * 1024 + sw0);
    a[m * 2 + 1] = *(const bf16x8*)(bufA + aBase + m * 1024 + sw1);
  }
#pragma unroll
  for (int ni = 0; ni < 2; ++ni) {
    b0[ni * 2 + 0] = *(const bf16x8*)(bufB + bBase + ni * 1024 + sw0);
    b0[ni * 2 + 1] = *(const bf16x8*)(bufB + bBase + ni * 1024 + sw1);
  }
  if constexpr (ISSUE) { stA(sp, 0, t + 1, buf ^ 1); stA(sp, 2, t + 1, buf ^ 1); }
  SCB();
  if constexpr (LAST) VMC(2); else VMC(4);
  BAR(); LGKM0();
  MFMA_Q(0, a, b0, 0);
  BAR(); SCB();

  // ---- phase 2: reads B-n1(4); MFMA (m0,n1)
#pragma unroll
  for (int ni = 0; ni < 2; ++ni) {
    b1[ni * 2 + 0] = *(const bf16x8*)(bufB + bBase + 8192 + ni * 1024 + sw0);
    b1[ni * 2 + 1] = *(const bf16x8*)(bufB + bBase + 8192 + ni * 1024 + sw1);
  }
  if constexpr (ISSUE) { stB(sp, 0, t + 1, buf ^ 1); stB(sp, 1, t + 1, buf ^ 1); }
  SCB();
  if constexpr (LAST) VMC(0); else VMC(4);
  BAR(); LGKM0();
  MFMA_Q(0, a, b1, 2);
  BAR(); SCB();

  // ---- phase 3: reads A-m1(8); MFMA (m1,n0)
#pragma unroll
  for (int m = 0; m < 4; ++m) {
    a[m * 2 + 0] = *(const bf16x8*)(bufA + aBase + 4096 + m * 1024 + sw0);
    a[m * 2 + 1] = *(const bf16x8*)(bufA + aBase + 4096 + m * 1024 + sw1);
  }
  if constexpr (ISSUE) { stB(sp, 2, t + 1, buf ^ 1); stB(sp, 3, t + 1, buf ^ 1); }
  SCB();
  BAR(); LGKM0();
  MFMA_Q(4, a, b0, 0);
  BAR(); SCB();

  // ---- phase 4: no reads; MFMA (m1,n1)
  if constexpr (ISSUE) {
    stA(sp, 1, t + 1, buf ^ 1); stA(sp, 3, t + 1, buf ^ 1);
    SCB();
    VMC(4);                      // certify G1,G2 of tile t+1 for next p1 reads
  }
  BAR();
  MFMA_Q(4, a, b1, 2);
  BAR(); SCB();
}

// C[M][N] = A[M][K] * B[N][K]^T + bias; 256x256, BK=64, m201-shape 4-phase tile
__global__ __launch_bounds__(THREADS, 2) void gemm_bf16(
    const ushort_t* __restrict__ A, const ushort_t* __restrict__ B,
    const float* __restrict__ bias, float* __restrict__ C) {
  extern __shared__ char smem[];

  const int nwg = (M_DIM / BM) * (N_DIM / BN);  // 512, %8==0 -> bijective
  int bid = blockIdx.x;
  int swz = (bid & 7) * (nwg >> 3) + (bid >> 3);
  int bx = swz & 15;
  int by = swz >> 4;
  const int tileM = by * BM;
  const int tileN = bx * BN;

  const int tid = threadIdx.x;
  const int lane = tid & 63;
  const int wave = tid >> 6;
  const int wrM = wave >> 2;    // 0..1 -> M offset wrM*128
  const int wcN = wave & 3;     // 0..3 -> N offset wcN*64

  // ---- staging source addressing (swizzle: 16B-slot ^= row&7, inverse on src)
  int q = tid >> 3;             // row within a 64-row round
  int slot = tid & 7;
  int scol = ((slot ^ (q & 7)) << 3);
  SP sp;
  sp.sm = smem;
  sp.wuni = wave << 10;
  sp.gA = A + (size_t)(tileM + q) * K_DIM + scol;
  // B row permutation (n-half-major): round base row = (q>>5)*64 + (q&31)
  int rB0 = ((q >> 5) << 6) + (q & 31);
  sp.gB = B + (size_t)(tileN + rB0) * K_DIM + scol;

  // ---- fragment read offsets: slot(kk,g) = ((kk*4+g) ^ (lrow&7)), elems=slot*8
  const int lrow = lane & 15;
  const int g = lane >> 4;
  const int l7 = lane & 7;
  const int sw0 = ((g ^ l7) << 3);
  const int sw1 = (((4 + g) ^ l7) << 3);
  const int aBase = (wrM * 128 + lrow) * 64;   // mh adds 4096, m adds 1024
  const int bBase = (wcN * 32 + lrow) * 64;    // nh adds 8192, ni adds 1024

  f32x4 acc[8][4];
#pragma unroll
  for (int m = 0; m < 8; ++m)
#pragma unroll
    for (int n = 0; n < 4; ++n) acc[m][n] = (f32x4)0.0f;

  // ---- prologue: stage tile 0 (G1..G4 order), certify G1,G2
  stA(sp, 0, 0, 0); stA(sp, 2, 0, 0);
  stB(sp, 0, 0, 0); stB(sp, 1, 0, 0);
  stB(sp, 2, 0, 0); stB(sp, 3, 0, 0);
  stA(sp, 1, 0, 0); stA(sp, 3, 0, 0);
  SCB();
  VMC(4);
  BAR(); SCB();

  for (int t = 0; t < NT - 1; ++t)
    ktile<true, false>(sp, t & 1, t, aBase, bBase, sw0, sw1, acc);
  ktile<false, true>(sp, (NT - 1) & 1, NT - 1, aBase, bBase, sw0, sw1, acc);

  // ---- epilogue: C/D layout col = lane&15, row = (lane>>4)*4 + reg
  const int orow = tileM + wrM * 128 + ((lane >> 4) << 2);
  const int ocol0 = tileN + wcN * 64 + lrow;
  float bv[4];
#pragma unroll
  for (int n = 0; n < 4; ++n) bv[n] = bias[ocol0 + n * 16];
#pragma unroll
  for (int m = 0; m < 8; ++m) {
#pragma unroll
    for (int n = 0; n < 4; ++n) {
      size_t base = (size_t)(orow + m * 16) * N_DIM + (ocol0 + n * 16);
#pragma unroll
      for (int r = 0; r < 4; ++r)
        C[base + (size_t)r * N_DIM] = acc[m][n][r] + bv[n];
    }
  }
}

extern "C" void kernel_launch(void* const* d_in, const int* in_sizes, int n_in,
                              void* d_out, int out_size, void* d_ws, size_t ws_size,
                              hipStream_t stream) {
  const float* x = (const float*)d_in[0];
  const float* cc = (const float*)d_in[1];
  const int* cl = (const int*)d_in[2];
  const float* rc = (const float*)d_in[3];
  const int* rl = (const int*)d_in[4];
  const float* bias = (const float*)d_in[5];
  float* out = (float*)d_out;

  ushort_t* Wbf = (ushort_t*)d_ws;                                  // 32 MB
  ushort_t* Xbf = (ushort_t*)d_ws + (size_t)N_DIM * K_DIM;          // 64 MB

  (void)hipFuncSetAttribute((const void*)gemm_bf16,
                            hipFuncAttributeMaxDynamicSharedMemorySize, SMEM_BYTES);

  dequant_w<<<NBLOCKS_VQ / 256, 256, 0, stream>>>(cc, cl, rc, rl, Wbf);
  cvt_x_bf16<<<(int)((M_DIM * (size_t)K_DIM / 8) / 256), 256, 0, stream>>>(x, Xbf);
  gemm_bf16<<<(M_DIM / BM) * (N_DIM / BN), THREADS, SMEM_BYTES, stream>>>(Xbf, Wbf, bias, out);
}

// Round 9
// 261.516 us; speedup vs baseline: 1.0606x; 1.0606x over previous
//
#include <hip/hip_runtime.h>
#include <hip/hip_bf16.h>
#include <stdint.h>

#define M_DIM 8192
#define N_DIM 4096
#define K_DIM 4096
#define BM 256
#define BN 256
#define BK 64
#define NT (K_DIM / BK)    // 64 K-tiles
#define THREADS 512
#define NBLOCKS_VQ (N_DIM * K_DIM / 16)

#define ABUF_B 32768       // one A (or B) K-tile: 256 x 64 x 2B
#define BREG   65536       // B region base
#define SMEM_BYTES 131072

typedef short bf16x8 __attribute__((ext_vector_type(8)));
typedef float f32x4 __attribute__((ext_vector_type(4)));
typedef unsigned short ushort_t;
typedef ushort_t ushort8 __attribute__((ext_vector_type(8)));

#define GLOBAL_AS __attribute__((address_space(1)))
#define LDS_AS __attribute__((address_space(3)))

__device__ __forceinline__ ushort_t f2bf(float f) {
  union { float f; uint32_t u; } v; v.f = f;
  uint32_t u = v.u;
  return (ushort_t)((u + 0x7FFFu + ((u >> 16) & 1u)) >> 16);
}

// ---------------- dequant: W[j][k] = coarse[cl[b]] + res[rl[b]], block b of 16
__global__ __launch_bounds__(256) void dequant_w(
    const float* __restrict__ cc, const int* __restrict__ cl,
    const float* __restrict__ rc, const int* __restrict__ rl,
    ushort_t* __restrict__ wout) {
  int b = blockIdx.x * 256 + threadIdx.x;
  int ci = cl[b];
  int ri = rl[b];
  const float4* c4 = (const float4*)(cc + (size_t)ci * 16);
  const float4* r4 = (const float4*)(rc + (size_t)ri * 16);
  float s[16];
#pragma unroll
  for (int p = 0; p < 4; ++p) {
    float4 a = c4[p];
    float4 r = r4[p];
    s[p * 4 + 0] = a.x + r.x;
    s[p * 4 + 1] = a.y + r.y;
    s[p * 4 + 2] = a.z + r.z;
    s[p * 4 + 3] = a.w + r.w;
  }
  ushort8 o0, o1;
#pragma unroll
  for (int j = 0; j < 8; ++j) o0[j] = f2bf(s[j]);
#pragma unroll
  for (int j = 0; j < 8; ++j) o1[j] = f2bf(s[8 + j]);
  ushort8* dst = (ushort8*)(wout + (size_t)b * 16);
  dst[0] = o0;
  dst[1] = o1;
}

// ---------------- x fp32 -> bf16
__global__ __launch_bounds__(256) void cvt_x_bf16(const float* __restrict__ x,
                                                  ushort_t* __restrict__ xb) {
  size_t i = (size_t)blockIdx.x * 256 + threadIdx.x;
  const float4* p = (const float4*)x + i * 2;
  float4 a = p[0];
  float4 b = p[1];
  ushort8 o;
  o[0] = f2bf(a.x); o[1] = f2bf(a.y); o[2] = f2bf(a.z); o[3] = f2bf(a.w);
  o[4] = f2bf(b.x); o[5] = f2bf(b.y); o[6] = f2bf(b.z); o[7] = f2bf(b.w);
  ((ushort8*)xb)[i] = o;
}

// ---------------- staging state
struct SP {
  const ushort_t* gA;  // per-thread A source (tile 0, inverse-swizzled col)
  const ushort_t* gB;  // per-thread B source (tile 0, permuted row, swz col)
  char* sm;
  int wuni;            // wave*1024 (wave-uniform LDS offset; HW appends lane*16)
};

__device__ __forceinline__ void stA(const SP& s, int r, int tile, int dbuf) {
  __builtin_amdgcn_global_load_lds(
      (const GLOBAL_AS void*)(s.gA + (size_t)tile * BK + (size_t)r * 64 * K_DIM),
      (LDS_AS void*)(s.sm + dbuf * ABUF_B + r * 8192 + s.wuni), 16, 0, 0);
}
__device__ __forceinline__ void stB(const SP& s, int r, int tile, int dbuf) {
  // LDS B row order is n-half-major: round r covers these global row offsets
  constexpr int roff[4] = {0, 128, 32, 160};
  __builtin_amdgcn_global_load_lds(
      (const GLOBAL_AS void*)(s.gB + (size_t)tile * BK + (size_t)roff[r] * K_DIM),
      (LDS_AS void*)(s.sm + BREG + dbuf * ABUF_B + r * 8192 + s.wuni), 16, 0, 0);
}

#define BAR()  __builtin_amdgcn_s_barrier()
#define SCB()  __builtin_amdgcn_sched_barrier(0)
#define VMC(n) asm volatile("s_waitcnt vmcnt(" #n ")" ::: "memory")

#define MFMA_Q(ACCM, AARR, BARR, ACCN)                                           \
  __builtin_amdgcn_s_setprio(1);                                                 \
  _Pragma("unroll")                                                              \
  for (int m = 0; m < 4; ++m)                                                    \
    _Pragma("unroll")                                                            \
    for (int ni = 0; ni < 2; ++ni) {                                             \
      acc[ACCM + m][ACCN + ni] = __builtin_amdgcn_mfma_f32_16x16x32_bf16(        \
          AARR[m * 2 + 0], BARR[ni * 2 + 0], acc[ACCM + m][ACCN + ni], 0, 0, 0); \
      acc[ACCM + m][ACCN + ni] = __builtin_amdgcn_mfma_f32_16x16x32_bf16(        \
          AARR[m * 2 + 1], BARR[ni * 2 + 1], acc[ACCM + m][ACCN + ni], 0, 0, 0); \
    }                                                                            \
  __builtin_amdgcn_s_setprio(0);

// Single-barrier K-tile: {vmcnt(0) [loads are 1 tile old -> non-blocking] ->
// BAR -> issue ALL 24 ds_reads -> issue 8 stages of t+1 -> SCB -> 4 MFMA
// quadrants}. Compiler emits partial lgkmcnt before each quadrant, so LDS
// reads stream under the MFMAs. Safety: a wave's tile-t reads complete before
// its last MFMA (lgkm), hence before its t+1-top barrier arrival; the
// overwrite of this buffer (tile t+2's stage) is issued after that barrier.
template<bool ISSUE>
__device__ __forceinline__ void ktile(const SP& sp, int buf, int t,
    int aBase, int bBase, int sw0, int sw1, f32x4 (&acc)[8][4]) {
  const ushort_t* bufA = (const ushort_t*)(sp.sm + buf * ABUF_B);
  const ushort_t* bufB = (const ushort_t*)(sp.sm + BREG + buf * ABUF_B);
  bf16x8 a0[8], a1[8], b0[4], b1[4];

  SCB(); VMC(0); BAR(); SCB();

  // ---- issue all fragment reads, consumption order Q1,Q2,Q3
#pragma unroll
  for (int m = 0; m < 4; ++m) {
    a0[m * 2 + 0] = *(const bf16x8*)(bufA + aBase + m * 1024 + sw0);
    a0[m * 2 + 1] = *(const bf16x8*)(bufA + aBase + m * 1024 + sw1);
  }
#pragma unroll
  for (int ni = 0; ni < 2; ++ni) {
    b0[ni * 2 + 0] = *(const bf16x8*)(bufB + bBase + ni * 1024 + sw0);
    b0[ni * 2 + 1] = *(const bf16x8*)(bufB + bBase + ni * 1024 + sw1);
  }
#pragma unroll
  for (int ni = 0; ni < 2; ++ni) {
    b1[ni * 2 + 0] = *(const bf16x8*)(bufB + bBase + 8192 + ni * 1024 + sw0);
    b1[ni * 2 + 1] = *(const bf16x8*)(bufB + bBase + 8192 + ni * 1024 + sw1);
  }
#pragma unroll
  for (int m = 0; m < 4; ++m) {
    a1[m * 2 + 0] = *(const bf16x8*)(bufA + aBase + 4096 + m * 1024 + sw0);
    a1[m * 2 + 1] = *(const bf16x8*)(bufA + aBase + 4096 + m * 1024 + sw1);
  }

  // ---- issue next tile's DMA (huge slack: consumed one full tile later)
  if constexpr (ISSUE) {
    stA(sp, 0, t + 1, buf ^ 1); stA(sp, 2, t + 1, buf ^ 1);
    stB(sp, 0, t + 1, buf ^ 1); stB(sp, 1, t + 1, buf ^ 1);
    stB(sp, 2, t + 1, buf ^ 1); stB(sp, 3, t + 1, buf ^ 1);
    stA(sp, 1, t + 1, buf ^ 1); stA(sp, 3, t + 1, buf ^ 1);
  }
  SCB();

  // ---- 4 MFMA quadrants; compiler inserts partial lgkm waits per quadrant
  MFMA_Q(0, a0, b0, 0);
  MFMA_Q(0, a0, b1, 2);
  MFMA_Q(4, a1, b0, 0);
  MFMA_Q(4, a1, b1, 2);
}

// C[M][N] = A[M][K] * B[N][K]^T + bias; 256x256, BK=64, 1-barrier pipelined tile
__global__ __launch_bounds__(THREADS, 2) void gemm_bf16(
    const ushort_t* __restrict__ A, const ushort_t* __restrict__ B,
    const float* __restrict__ bias, float* __restrict__ C) {
  extern __shared__ char smem[];

  const int nwg = (M_DIM / BM) * (N_DIM / BN);  // 512, %8==0 -> bijective
  int bid = blockIdx.x;
  int swz = (bid & 7) * (nwg >> 3) + (bid >> 3);
  int bx = swz & 15;
  int by = swz >> 4;
  const int tileM = by * BM;
  const int tileN = bx * BN;

  const int tid = threadIdx.x;
  const int lane = tid & 63;
  const int wave = tid >> 6;
  const int wrM = wave >> 2;    // 0..1 -> M offset wrM*128
  const int wcN = wave & 3;     // 0..3 -> N offset wcN*64

  // ---- staging source addressing (swizzle: 16B-slot ^= row&7, inverse on src)
  int q = tid >> 3;             // row within a 64-row round
  int slot = tid & 7;
  int scol = ((slot ^ (q & 7)) << 3);
  SP sp;
  sp.sm = smem;
  sp.wuni = wave << 10;
  sp.gA = A + (size_t)(tileM + q) * K_DIM + scol;
  // B row permutation (n-half-major): round base row = (q>>5)*64 + (q&31)
  int rB0 = ((q >> 5) << 6) + (q & 31);
  sp.gB = B + (size_t)(tileN + rB0) * K_DIM + scol;

  // ---- fragment read offsets: slot(kk,g) = ((kk*4+g) ^ (lrow&7)), elems=slot*8
  const int lrow = lane & 15;
  const int g = lane >> 4;
  const int l7 = lane & 7;
  const int sw0 = ((g ^ l7) << 3);
  const int sw1 = (((4 + g) ^ l7) << 3);
  const int aBase = (wrM * 128 + lrow) * 64;   // mh adds 4096, m adds 1024
  const int bBase = (wcN * 32 + lrow) * 64;    // nh adds 8192, ni adds 1024

  f32x4 acc[8][4];
#pragma unroll
  for (int m = 0; m < 8; ++m)
#pragma unroll
    for (int n = 0; n < 4; ++n) acc[m][n] = (f32x4)0.0f;

  // ---- prologue: stage tile 0 into buf0
  stA(sp, 0, 0, 0); stA(sp, 2, 0, 0);
  stB(sp, 0, 0, 0); stB(sp, 1, 0, 0);
  stB(sp, 2, 0, 0); stB(sp, 3, 0, 0);
  stA(sp, 1, 0, 0); stA(sp, 3, 0, 0);

  for (int t = 0; t < NT - 1; ++t)
    ktile<true>(sp, t & 1, t, aBase, bBase, sw0, sw1, acc);
  ktile<false>(sp, (NT - 1) & 1, NT - 1, aBase, bBase, sw0, sw1, acc);

  // ---- epilogue: C/D layout col = lane&15, row = (lane>>4)*4 + reg
  const int orow = tileM + wrM * 128 + ((lane >> 4) << 2);
  const int ocol0 = tileN + wcN * 64 + lrow;
  float bv[4];
#pragma unroll
  for (int n = 0; n < 4; ++n) bv[n] = bias[ocol0 + n * 16];
#pragma unroll
  for (int m = 0; m < 8; ++m) {
#pragma unroll
    for (int n = 0; n < 4; ++n) {
      size_t base = (size_t)(orow + m * 16) * N_DIM + (ocol0 + n * 16);
#pragma unroll
      for (int r = 0; r < 4; ++r)
        C[base + (size_t)r * N_DIM] = acc[m][n][r] + bv[n];
    }
  }
}

extern "C" void kernel_launch(void* const* d_in, const int* in_sizes, int n_in,
                              void* d_out, int out_size, void* d_ws, size_t ws_size,
                              hipStream_t stream) {
  const float* x = (const float*)d_in[0];
  const float* cc = (const float*)d_in[1];
  const int* cl = (const int*)d_in[2];
  const float* rc = (const float*)d_in[3];
  const int* rl = (const int*)d_in[4];
  const float* bias = (const float*)d_in[5];
  float* out = (float*)d_out;

  ushort_t* Wbf = (ushort_t*)d_ws;                                  // 32 MB
  ushort_t* Xbf = (ushort_t*)d_ws + (size_t)N_DIM * K_DIM;          // 64 MB

  (void)hipFuncSetAttribute((const void*)gemm_bf16,
                            hipFuncAttributeMaxDynamicSharedMemorySize, SMEM_BYTES);

  dequant_w<<<NBLOCKS_VQ / 256, 256, 0, stream>>>(cc, cl, rc, rl, Wbf);
  cvt_x_bf16<<<(int)((M_DIM * (size_t)K_DIM / 8) / 256), 256, 0, stream>>>(x, Xbf);
  gemm_bf16<<<(M_DIM / BM) * (N_DIM / BN), THREADS, SMEM_BYTES, stream>>>(Xbf, Wbf, bias, out);
}